// Round 3
// baseline (111.134 us; speedup 1.0000x reference)
//
#include <hip/hip_runtime.h>
#include <hip/hip_bf16.h>

#define NB 8
#define NT 2048
#define NC 1024
#define NH 64

typedef __attribute__((ext_vector_type(8))) short bf16x8;
typedef __attribute__((ext_vector_type(4))) short bf16x4;
typedef __attribute__((ext_vector_type(4))) float f32x4;

__device__ __forceinline__ unsigned short f2bf(float f) {
  __hip_bfloat16 h = __float2bfloat16(f);
  return __builtin_bit_cast(unsigned short, h);
}

__device__ __forceinline__ f32x4 mfma32(bf16x8 a, bf16x8 b, f32x4 c) {
  return __builtin_amdgcn_mfma_f32_16x16x32_bf16(a, b, c, 0, 0, 0);
}

#if __has_builtin(__builtin_amdgcn_mfma_f32_16x16x16bf16_1k)
__device__ __forceinline__ f32x4 mfma16(bf16x4 a, bf16x4 b, f32x4 c) {
  return __builtin_amdgcn_mfma_f32_16x16x16bf16_1k(a, b, c, 0, 0, 0);
}
#else
__device__ __forceinline__ f32x4 mfma16(bf16x4 a, bf16x4 b, f32x4 c) {
  asm volatile("v_mfma_f32_16x16x16_bf16 %0, %1, %2, %0\n\ts_nop 7"
               : "+v"(c) : "v"(a), "v"(b));
  return c;
}
#endif

// ---------------------------------------------------------------------------
// Kernel 0: weight transpose+convert. W[1024][64] f32 -> Wt[64][1024] bf16.
// Folds softmax scale * log2(e) into Wq so attention can use exp2 directly.
// ---------------------------------------------------------------------------
__global__ __launch_bounds__(256) void wt_kernel(const float* __restrict__ Wq,
                                                 const float* __restrict__ Wk,
                                                 const float* __restrict__ Wv,
                                                 unsigned short* __restrict__ Wt) {
  __shared__ float lds[64][65];
  int wi = blockIdx.x >> 4, kt = blockIdx.x & 15;
  const float* W = (wi == 0) ? Wq : ((wi == 1) ? Wk : Wv);
  float scale = (wi == 0) ? 0.18033688011112043f : 1.0f;  // 0.125 * log2(e)
  int tid = threadIdx.x;
#pragma unroll
  for (int i = 0; i < 16; ++i) {
    int idx = tid + i * 256;
    lds[idx >> 6][idx & 63] = W[(size_t)(kt * 64 + (idx >> 6)) * NH + (idx & 63)] * scale;
  }
  __syncthreads();
#pragma unroll
  for (int i = 0; i < 16; ++i) {
    int idx = tid + i * 256;
    int n = idx >> 6, kk = idx & 63;
    Wt[(size_t)(wi * 64 + n) * NC + kt * 64 + kk] = f2bf(lds[kk][n]);
  }
}

// ---------------------------------------------------------------------------
// Kernel 1: fused QKV projection, v3.
// 512 blocks x 512 thr (8 waves -> 4 waves/SIMD). Block = 32 rows; x staged
// in LDS (bf16, XOR swizzle byte^=(row&7)<<4) in two K=512 phases. Wave w
// owns row-half rf=w&1 and n-cols [(w>>1)*16, +16) of q,k,v: per K-step
// 1 ds_read_b128 + 3 global 16B weight loads + 3 MFMA.
// ---------------------------------------------------------------------------
__global__ __launch_bounds__(512) void proj_kernel(const float* __restrict__ x,
                                                   const unsigned short* __restrict__ Wt,
                                                   unsigned short* __restrict__ qo,
                                                   unsigned short* __restrict__ ko,
                                                   unsigned short* __restrict__ vo) {
  __shared__ __align__(16) unsigned short xs[32 * 512];  // 32KB, swizzled
  __shared__ __align__(16) unsigned short vlds[64][40];

  int tid = threadIdx.x;
  int lane = tid & 63, w = tid >> 6;
  int ln = lane & 15, g = lane >> 4;
  int rf = w & 1;                 // row-half (16 rows)
  int cs = w >> 1;                // col-slice (16 of 64 head cols)
  int row0 = blockIdx.x * 32;

  int nc = cs * 16 + ln;
  const unsigned short* wpq = Wt + (size_t)(0 * 64 + nc) * NC;
  const unsigned short* wpk = Wt + (size_t)(1 * 64 + nc) * NC;
  const unsigned short* wpv = Wt + (size_t)(2 * 64 + nc) * NC;

  f32x4 acc[3];
#pragma unroll
  for (int j = 0; j < 3; ++j) acc[j] = (f32x4){0.f, 0.f, 0.f, 0.f};

  for (int kk = 0; kk < 2; ++kk) {
    // ---- stage x[32][512] f32 -> bf16 LDS (swizzled)
    {
      int r4 = tid >> 7;            // 0..3
      int c4 = (tid & 127) * 4;     // 0..508
      const float* xp = x + (size_t)row0 * NC + kk * 512 + c4;
#pragma unroll
      for (int i = 0; i < 8; ++i) {
        int row = i * 4 + r4;
        float4 v4 = *(const float4*)(xp + (size_t)row * NC);
        bf16x4 b4;
        b4[0] = (short)f2bf(v4.x); b4[1] = (short)f2bf(v4.y);
        b4[2] = (short)f2bf(v4.z); b4[3] = (short)f2bf(v4.w);
        int byte = (row * 1024 + c4 * 2) ^ ((row & 7) << 4);
        *(bf16x4*)((char*)xs + byte) = b4;
      }
    }
    __syncthreads();
    // ---- MFMA over this K-phase
#pragma unroll 4
    for (int c0 = 0; c0 < 512; c0 += 32) {
      int row = rf * 16 + ln;
      int byte = (row * 1024 + (c0 + g * 8) * 2) ^ ((row & 7) << 4);
      bf16x8 a = *(const bf16x8*)((char*)xs + byte);
      int kg = kk * 512 + c0 + g * 8;
      bf16x8 bq = *(const bf16x8*)(wpq + kg);
      bf16x8 bk = *(const bf16x8*)(wpk + kg);
      bf16x8 bv = *(const bf16x8*)(wpv + kg);
      acc[0] = mfma32(a, bq, acc[0]);
      acc[1] = mfma32(a, bk, acc[1]);
      acc[2] = mfma32(a, bv, acc[2]);
    }
    __syncthreads();
  }

  // ---- epilogue: q,k direct; v via LDS transpose
#pragma unroll
  for (int r = 0; r < 4; ++r) {
    int row = row0 + rf * 16 + g * 4 + r;
    qo[(size_t)row * NH + nc] = f2bf(acc[0][r]);
    ko[(size_t)row * NH + nc] = f2bf(acc[1][r]);
    vlds[nc][rf * 16 + g * 4 + r] = f2bf(acc[2][r]);
  }
  __syncthreads();
  if (tid < 256) {
    int b = row0 / NT, t0b = row0 % NT;
    int hh = tid >> 2, ts = (tid & 3) * 8;
    *(bf16x8*)(vo + (size_t)(b * NH + hh) * NT + t0b + ts) = *(const bf16x8*)&vlds[hh][ts];
  }
}

// ---------------------------------------------------------------------------
// Kernel 2: causal flash attention, v3. Swapped QK^T (S^T = mfma(K,Q)) chains
// into PV's B-operand with zero shuffles. 4-way key-split: block = one
// 16-query subtile, wave ks handles 64-key chunks s0 % 256 == ks*64, private
// online-softmax state, folded by wave 0 via LDS. 1024 blocks x 256 thr
// -> 4 waves/SIMD. Defer-rescale (THR=8 base-2) skips the O-rescale when the
// running max hasn't grown materially.
// ---------------------------------------------------------------------------
__global__ __launch_bounds__(256) void attn_kernel(const unsigned short* __restrict__ qw,
                                                   const unsigned short* __restrict__ kw,
                                                   const unsigned short* __restrict__ vw,
                                                   float* __restrict__ out) {
  int tid = threadIdx.x;
  int lane = tid & 63, ks = tid >> 6;
  int ln = lane & 15, g = lane >> 4;
  int bid = blockIdx.x;
  int half = bid >> 9, idx = bid & 511;
  int b = idx >> 6, jj = idx & 63;
  int qtile = half ? (127 - jj) : jj;   // pairing swizzle: balanced causal work
  int t0 = qtile * 16;
  int tq = t0 + ln;

  const unsigned short* qp = qw + (size_t)(b * NT + tq) * NH + g * 8;
  bf16x8 qf0 = *(const bf16x8*)(qp);
  bf16x8 qf1 = *(const bf16x8*)(qp + 32);

  const unsigned short* kb = kw + (size_t)b * NT * NH + g * 8;
  const unsigned short* vb = vw + (size_t)b * NH * NT;

  f32x4 oacc[4];
#pragma unroll
  for (int i = 0; i < 4; ++i) oacc[i] = (f32x4){0.f, 0.f, 0.f, 0.f};
  float m = -1e30f, lsum = 0.f;

  int send = t0 + 16;                          // exclusive key bound
  for (int s0 = ks * 64; s0 < send; s0 += 256) {
    // ---- S^T = K_tile x Q^T
    f32x4 st4[4];
#pragma unroll
    for (int st = 0; st < 4; ++st) {
      const unsigned short* kp = kb + (size_t)(s0 + st * 16 + ln) * NH;
      bf16x8 k0 = *(const bf16x8*)(kp);
      bf16x8 k1 = *(const bf16x8*)(kp + 32);
      f32x4 a = (f32x4){0.f, 0.f, 0.f, 0.f};
      a = mfma32(k0, qf0, a);
      a = mfma32(k1, qf1, a);
      st4[st] = a;
    }
    // ---- causal mask (wave-uniform branch)
    if (s0 + 63 > t0) {
#pragma unroll
      for (int st = 0; st < 4; ++st)
#pragma unroll
        for (int r = 0; r < 4; ++r)
          if (s0 + st * 16 + g * 4 + r > tq) st4[st][r] = -1e30f;
    }
    // ---- online softmax (base-2 logits) with deferred rescale
    float tmax = -1e30f;
#pragma unroll
    for (int st = 0; st < 4; ++st)
#pragma unroll
      for (int r = 0; r < 4; ++r) tmax = fmaxf(tmax, st4[st][r]);
    tmax = fmaxf(tmax, __shfl_xor(tmax, 16));
    tmax = fmaxf(tmax, __shfl_xor(tmax, 32));
    if (__any(tmax > m + 8.f)) {
      float mnew = fmaxf(m, tmax);
      float sfac = exp2f(m - mnew);
      lsum *= sfac;
#pragma unroll
      for (int hf = 0; hf < 4; ++hf)
#pragma unroll
        for (int r = 0; r < 4; ++r) oacc[hf][r] *= sfac;
      m = mnew;
    }

    float psum = 0.f;
    bf16x4 pb[4];
#pragma unroll
    for (int st = 0; st < 4; ++st) {
#pragma unroll
      for (int r = 0; r < 4; ++r) {
        float p = exp2f(st4[st][r] - m);
        psum += p;
        pb[st][r] = (short)f2bf(p);
      }
    }
    psum += __shfl_xor(psum, 16);
    psum += __shfl_xor(psum, 32);
    lsum += psum;

    // ---- PV: out^T[h][t] += vT x P^T
#pragma unroll
    for (int hf = 0; hf < 4; ++hf) {
      const unsigned short* vp = vb + (size_t)(hf * 16 + ln) * NT + s0 + g * 4;
#pragma unroll
      for (int st = 0; st < 4; ++st) {
        bf16x4 va = *(const bf16x4*)(vp + st * 16);
        oacc[hf] = mfma16(va, pb[st], oacc[hf]);
      }
    }
  }

  // ---- fold the 4 key-split partials (wave 0 accumulates)
  __shared__ float mbuf[3][64][20];
  __shared__ float olds[16][68];
  if (ks) {
    float* d = mbuf[ks - 1][lane];
    d[0] = m; d[1] = lsum;
#pragma unroll
    for (int hf = 0; hf < 4; ++hf)
#pragma unroll
      for (int r = 0; r < 4; ++r) d[2 + hf * 4 + r] = oacc[hf][r];
  }
  __syncthreads();
  if (ks == 0) {
#pragma unroll
    for (int j = 0; j < 3; ++j) {
      const float* d = mbuf[j][lane];
      float mB = d[0], lB = d[1];
      float mx = fmaxf(m, mB);
      float fA = exp2f(m - mx), fB = exp2f(mB - mx);
      lsum = lsum * fA + lB * fB;
#pragma unroll
      for (int hf = 0; hf < 4; ++hf)
#pragma unroll
        for (int r = 0; r < 4; ++r)
          oacc[hf][r] = oacc[hf][r] * fA + d[2 + hf * 4 + r] * fB;
      m = mx;
    }
    float inv = 1.f / lsum;
#pragma unroll
    for (int hf = 0; hf < 4; ++hf)
#pragma unroll
      for (int r = 0; r < 4; ++r)
        olds[ln][hf * 16 + g * 4 + r] = oacc[hf][r] * inv;
  }
  __syncthreads();
  // ---- transposed store out[b][t][h]
  if (tid < 64) {
    int tl = tid >> 2, h0 = (tid & 3) * 16;
    size_t obase = (size_t)(b * NT + t0 + tl) * NH + h0;
#pragma unroll
    for (int vv = 0; vv < 4; ++vv) {
      float4 t4 = make_float4(olds[tl][h0 + vv * 4 + 0], olds[tl][h0 + vv * 4 + 1],
                              olds[tl][h0 + vv * 4 + 2], olds[tl][h0 + vv * 4 + 3]);
      *(float4*)(out + obase + vv * 4) = t4;
    }
  }
}

// ---------------------------------------------------------------------------
extern "C" void kernel_launch(void* const* d_in, const int* in_sizes, int n_in,
                              void* d_out, int out_size, void* d_ws, size_t ws_size,
                              hipStream_t stream) {
  const float* x  = (const float*)d_in[0];
  const float* Wq = (const float*)d_in[1];
  const float* Wk = (const float*)d_in[2];
  const float* Wv = (const float*)d_in[3];
  float* out = (float*)d_out;

  unsigned short* Wt = (unsigned short*)d_ws;
  unsigned short* q  = (unsigned short*)((char*)d_ws + (1 << 19));
  unsigned short* k  = q + (size_t)NB * NT * NH;
  unsigned short* v  = k + (size_t)NB * NT * NH;

  wt_kernel<<<48, 256, 0, stream>>>(Wq, Wk, Wv, Wt);
  proj_kernel<<<(NB * NT) / 32, 512, 0, stream>>>(x, Wt, q, k, v);
  attn_kernel<<<1024, 256, 0, stream>>>(q, k, v, out);
}